// Round 2
// 129.215 us; speedup vs baseline: 1.0002x; 1.0002x over previous
//
#include <hip/hip_runtime.h>
#include <hip/hip_bf16.h>

#define HH 1024
#define LL 512
#define TNT 8              // 512/64 row-tiles
#define NTILE 36           // TNT*(TNT+1)/2 triangular 64x64 tiles

typedef __attribute__((ext_vector_type(8))) short bf16x8;
typedef __attribute__((ext_vector_type(4))) float f32x4;
typedef __attribute__((ext_vector_type(2))) float f32x2;

static constexpr float C_EXP = 2.8853900817779268f; // 2*log2(e)

// pack 8 fp32 -> 8 bf16 (RNE) as uint4
static __device__ __forceinline__ uint4 pack8(float4 a, float4 b) {
    union { uint4 u; __hip_bfloat162 h[4]; } r;
    r.h[0] = __float22bfloat162_rn(make_float2(a.x, a.y));
    r.h[1] = __float22bfloat162_rn(make_float2(a.z, a.w));
    r.h[2] = __float22bfloat162_rn(make_float2(b.x, b.y));
    r.h[3] = __float22bfloat162_rn(make_float2(b.z, b.w));
    return r.u;
}

static __device__ __forceinline__ f32x2 lo2(const float4& v) { return (f32x2){v.x, v.y}; }
static __device__ __forceinline__ f32x2 hi2(const float4& v) { return (f32x2){v.z, v.w}; }

// ---------------------------------------------------------------------------
// Kernel 1: bf16 MFMA projection (unchanged — measured-good form).
//   n < 1024:  Ea[m][n] = exp2(C*(acc+b1[n]));  else Eb[m][n-1024] = exp2(C*acc)
// ---------------------------------------------------------------------------
__global__ __launch_bounds__(256, 4) void proj_mfma_kernel(
    const float* __restrict__ lm, const float* __restrict__ W1,
    const float* __restrict__ b1, float* __restrict__ Ea, float* __restrict__ Eb)
{
    __shared__ ushort As[64][136];  // 136 us = 68 dw = 4 mod 32 banks: <=2-way, free
    __shared__ ushort Bs[64][136];

    const int tid  = threadIdx.x;
    const int lane = tid & 63;
    const int w    = tid >> 6;
    const int b    = blockIdx.x;          // 0..255
    const int xcd  = b & 7;
    const int idx  = b >> 3;              // 0..31
    const int nbase = (xcd * 4 + (idx & 3)) * 64;   // 0..2047
    const int mbase = (idx >> 2) * 64;              // 0..448
    const int wm   = w * 16;
    const int sel  = nbase >> 10;         // block-uniform: Wa(0)/Wb(1)
    const int nrow = nbase & 1023;

    const int frow = lane & 15;
    const int q8   = (lane >> 4) * 8;

    f32x4 acc[4] = {};

    for (int kb = 0; kb < HH; kb += 128) {
        __syncthreads();
        {
            int p = tid;
#pragma unroll
            for (int it = 0; it < 4; ++it, p += 256) {
                const int row = p >> 4, c8 = (p & 15) * 8;
                const float* pa = &lm[(mbase + row) * HH + kb + c8];
                *(uint4*)&As[row][c8] = pack8(*(const float4*)pa, *(const float4*)(pa + 4));
                const float* pw = &W1[(nrow + row) * 2048 + sel * 1024 + kb + c8];
                *(uint4*)&Bs[row][c8] = pack8(*(const float4*)pw, *(const float4*)(pw + 4));
            }
        }
        __syncthreads();

#pragma unroll
        for (int s = 0; s < 4; ++s) {
            const bf16x8 a = *(const bf16x8*)&As[wm + frow][s * 32 + q8];
#pragma unroll
            for (int nf = 0; nf < 4; ++nf) {
                const bf16x8 bb = *(const bf16x8*)&Bs[nf * 16 + frow][s * 32 + q8];
                acc[nf] = __builtin_amdgcn_mfma_f32_16x16x32_bf16(a, bb, acc[nf], 0, 0, 0);
            }
        }
    }

    // D mapping: col=lane&15 (n), row=(lane>>4)*4+reg (m)
    const int col = lane & 15;
    const int rq  = (lane >> 4) * 4;
    const int m0  = mbase + wm + rq;
    const bool isA = sel == 0;            // block-uniform
#pragma unroll
    for (int nf = 0; nf < 4; ++nf) {
        const int nn = (nrow + nf * 16 + col);
        if (isA) {
            const float bb = b1[nn];
#pragma unroll
            for (int r = 0; r < 4; ++r)
                Ea[(m0 + r) * HH + nn] = __builtin_amdgcn_exp2f(C_EXP * (acc[nf][r] + bb));
        } else {
#pragma unroll
            for (int r = 0; r < 4; ++r)
                Eb[(m0 + r) * HH + nn] = __builtin_amdgcn_exp2f(C_EXP * acc[nf][r]);
        }
    }
}

// ---------------------------------------------------------------------------
// Kernel 2: triangular pairwise contraction, 64x64 tile, 4x4 per thread.
//  - f32x2 lanes pack ADJACENT h (natural .xy/.zw of ds_read_b128) so the
//    compiler can emit true v_pk_fma_f32 (no cross-reg marshaling).
//  - 1/d + 1/e folded to (d+e)/(d*e): one rcp per pair per 4h (1 rcp/8 elems).
//  - LDS: 4 tiles x 64 rows x 32 h = 32 KB; rows are 128 B so columns are
//    bank-aliased -> XOR float4-slot swizzle (slot ^= row&7): all reads
//    <=2-way (free), both j-side (16 rows/wave) and i-side (4-row broadcast).
//  - reads/element halves vs 32x32 tiling (16 b128 per h4 serve 128 elems).
// ---------------------------------------------------------------------------
__global__ __launch_bounds__(256, 3) void pair_kernel(
    const float* __restrict__ Ea, const float* __restrict__ Eb,
    const float* __restrict__ W2, float* __restrict__ pbuf, int slice)
{
    __shared__ float tl[4][64][32];   // [0]=Ea[j] [1]=Eb[j] [2]=Ea[i] [3]=Eb[i]

    const int tid = threadIdx.x;
    const int tx  = tid & 15;
    const int ty  = tid >> 4;         // 0..15

    int tt = blockIdx.x, bi = 0, rem = TNT;          // triangular decode
    while (tt >= rem) { tt -= rem; --rem; ++bi; }
    const int bj    = bi + tt;
    const int ibase = bi * 64;
    const int jbase = bj * 64;
    const int k0    = blockIdx.y * slice;

    f32x2 acc0[4][4] = {};   // [ii][jj], h-packed partial sums, channel 0
    f32x2 acc1[4][4] = {};   // channel 1
    const f32x2 one2 = {1.f, 1.f};

    for (int kb = 0; kb < slice; kb += 32) {
        if (kb) __syncthreads();
        {   // stage 4 tiles x 64 rows x 32 floats = 2048 float4, 8/thread
            const int c4  = tid & 7;
            const int r0  = tid >> 3;                // 0..31
            const int hof = k0 + kb + c4 * 4;
#pragma unroll
            for (int it = 0; it < 8; ++it) {
                const int tile = it >> 1;            // compile-time per it
                const int row  = (it & 1) * 32 + r0;
                const int base = (tile < 2) ? jbase : ibase;
                const float* src = (tile == 0 || tile == 2) ? Ea : Eb;
                const int c4s = c4 ^ (row & 7);
                *(float4*)&tl[tile][row][c4s * 4] =
                    *(const float4*)&src[(size_t)(base + row) * HH + hof];
            }
        }
        __syncthreads();

#pragma unroll 2
        for (int h4 = 0; h4 < 8; ++h4) {
            const int sxj = (h4 ^ (tx & 7)) * 4;     // xor-swizzled float4 slot
            const int sxi = (h4 ^ (ty & 7)) * 4;
            float4 Aj[4], Bj[4], Ai[4], Bi[4];
#pragma unroll
            for (int jj = 0; jj < 4; ++jj) {         // 16 distinct rows/wave, 2-way max
                Aj[jj] = *(const float4*)&tl[0][tx + 16 * jj][sxj];
                Bj[jj] = *(const float4*)&tl[1][tx + 16 * jj][sxj];
            }
#pragma unroll
            for (int ii = 0; ii < 4; ++ii) {         // 4-row broadcast reads
                Ai[ii] = *(const float4*)&tl[2][ty + 16 * ii][sxi];
                Bi[ii] = *(const float4*)&tl[3][ty + 16 * ii][sxi];
            }
            const float4 w0q = *(const float4*)&W2[k0 + kb + h4 * 4];      // uniform
            const float4 w1q = *(const float4*)&W2[HH + k0 + kb + h4 * 4];
            const f32x2 w0lo = lo2(w0q), w0hi = hi2(w0q);
            const f32x2 w1lo = lo2(w1q), w1hi = hi2(w1q);

#pragma unroll
            for (int ii = 0; ii < 4; ++ii) {
                const f32x2 ailo = lo2(Ai[ii]), aihi = hi2(Ai[ii]);
                const f32x2 bilo = lo2(Bi[ii]), bihi = hi2(Bi[ii]);
#pragma unroll
                for (int jj = 0; jj < 4; ++jj) {
                    // d = 1 + Eb_i*Ea_j ; e = 1 + Ea_i*Eb_j   (h-packed pairs)
                    const f32x2 d01 = __builtin_elementwise_fma(bilo, lo2(Aj[jj]), one2);
                    const f32x2 d23 = __builtin_elementwise_fma(bihi, hi2(Aj[jj]), one2);
                    const f32x2 e01 = __builtin_elementwise_fma(ailo, lo2(Bj[jj]), one2);
                    const f32x2 e23 = __builtin_elementwise_fma(aihi, hi2(Bj[jj]), one2);
                    // 1/d + 1/e = (d+e)/(d*e); batch-rcp the 4 products (>=1, no uflow)
                    const f32x2 n01 = d01 + e01, n23 = d23 + e23;
                    const f32x2 m01 = d01 * e01, m23 = d23 * e23;
                    const float p01 = m01.x * m01.y;
                    const float p23 = m23.x * m23.y;
                    const float R   = __builtin_amdgcn_rcpf(p01 * p23);
                    const float r01 = R * p23;       // = 1/p01
                    const float r23 = R * p01;       // = 1/p23
                    const f32x2 u01 = (n01 * __builtin_shufflevector(m01, m01, 1, 0))
                                      * (f32x2){r01, r01};
                    const f32x2 u23 = (n23 * __builtin_shufflevector(m23, m23, 1, 0))
                                      * (f32x2){r23, r23};
                    acc0[ii][jj] = __builtin_elementwise_fma(u01, w0lo, acc0[ii][jj]);
                    acc0[ii][jj] = __builtin_elementwise_fma(u23, w0hi, acc0[ii][jj]);
                    acc1[ii][jj] = __builtin_elementwise_fma(u01, w1lo, acc1[ii][jj]);
                    acc1[ii][jj] = __builtin_elementwise_fma(u23, w1hi, acc1[ii][jj]);
                }
            }
        }
    }

    float* pb = pbuf + ((size_t)blockIdx.y * NTILE + blockIdx.x) * 8192;
#pragma unroll
    for (int ii = 0; ii < 4; ++ii)
#pragma unroll
        for (int jj = 0; jj < 4; ++jj) {
            const int li = ty + 16 * ii, lj = tx + 16 * jj;
            const f32x2 v = { acc0[ii][jj].x + acc0[ii][jj].y,
                              acc1[ii][jj].x + acc1[ii][jj].y };
            *(f32x2*)&pb[(li * 64 + lj) * 2] = v;
        }
}

// ---------------------------------------------------------------------------
// Kernel 3: combine: out = wsum[c]+b2[c] - sum_z pbuf; scatter (i,j),(j,i).
// 1152 blocks over 36 tiles x 64x64x2; 4-way ILP on z.
// ---------------------------------------------------------------------------
__global__ __launch_bounds__(256) void combine_kernel(
    const float* __restrict__ pbuf, const float* __restrict__ W2,
    const float* __restrict__ b2, float* __restrict__ out, int nz)
{
    __shared__ float s_ws[2];

    const int tid = threadIdx.x;
    if (tid < 128) {
        const int c = tid >> 6, l = tid & 63;
        float s = 0.f;
#pragma unroll
        for (int q = 0; q < 4; ++q) {
            const float4 v = *(const float4*)&W2[c * HH + (l + q * 64) * 4];
            s += v.x + v.y + v.z + v.w;
        }
#pragma unroll
        for (int off = 32; off; off >>= 1) s += __shfl_down(s, off, 64);
        if (l == 0) s_ws[c] = s + b2[c];
    }
    __syncthreads();

    const int idx   = blockIdx.x * 256 + tid;   // 0 .. 36*8192-1
    const int t     = idx >> 13;                // block-uniform (8192/256=32)
    const int local = idx & 8191;
    int tt = t, bi = 0, rem = TNT;
    while (tt >= rem) { tt -= rem; --rem; ++bi; }
    const int bj = bi + tt;

    float s0 = 0.f, s1 = 0.f, s2 = 0.f, s3 = 0.f;
    for (int z = 0; z < nz; z += 4) {   // nz in {8,16,32}
        s0 += pbuf[((size_t)z * NTILE + t) * 8192 + local];
        s1 += pbuf[((size_t)(z + 1) * NTILE + t) * 8192 + local];
        s2 += pbuf[((size_t)(z + 2) * NTILE + t) * 8192 + local];
        s3 += pbuf[((size_t)(z + 3) * NTILE + t) * 8192 + local];
    }
    const float s = (s0 + s1) + (s2 + s3);

    const int li = local >> 7;          // 0..63
    const int lj = (local >> 1) & 63;
    const int c  = local & 1;
    const float v = s_ws[c] - s;

    const int i = bi * 64 + li;
    const int j = bj * 64 + lj;
    out[(i * LL + j) * 2 + c] = v;
    out[(j * LL + i) * 2 + c] = v;   // diagonal tiles: same-value rewrite, benign
}

extern "C" void kernel_launch(void* const* d_in, const int* in_sizes, int n_in,
                              void* d_out, int out_size, void* d_ws, size_t ws_size,
                              hipStream_t stream)
{
    const float* lm = (const float*)d_in[0];
    const float* W1 = (const float*)d_in[1];
    const float* b1 = (const float*)d_in[2];
    const float* W2 = (const float*)d_in[3];
    const float* b2 = (const float*)d_in[4];
    float* out = (float*)d_out;

    char* ws = (char*)d_ws;
    float* Ea   = (float*)ws;                            // 2 MB
    float* Eb   = (float*)(ws + (2u << 20));             // 2 MB
    float* pbuf = (float*)(ws + (4u << 20) + 64);        // nz * 1.18 MB

    const size_t ubase = (4u << 20) + 64;
    const size_t per_z = (size_t)NTILE * 8192 * 4;       // 1.18 MB per z-slice
    int nz = 8;                                          // 288 blocks (safe floor)
    if      (ws_size >= ubase + 32 * per_z) nz = 32;     // 1152 blocks, 4.5/CU
    else if (ws_size >= ubase + 16 * per_z) nz = 16;     // 576 blocks
    const int slice = HH / nz;

    proj_mfma_kernel<<<256, 256, 0, stream>>>(lm, W1, b1, Ea, Eb);
    pair_kernel<<<dim3(NTILE, nz), 256, 0, stream>>>(Ea, Eb, W2, pbuf, slice);
    combine_kernel<<<(NTILE * 8192) / 256, 256, 0, stream>>>(pbuf, W2, b2, out, nz);
}

// Round 3
// 128.958 us; speedup vs baseline: 1.0022x; 1.0020x over previous
//
#include <hip/hip_runtime.h>
#include <hip/hip_bf16.h>

#define HH 1024
#define LL 512
#define TNT 8              // 512/64 row-tiles
#define NTILE 36           // TNT*(TNT+1)/2 triangular 64x64 tiles

typedef __attribute__((ext_vector_type(8))) short bf16x8;
typedef __attribute__((ext_vector_type(4))) float f32x4;
typedef __attribute__((ext_vector_type(2))) float f32x2;

static constexpr float C_EXP = 2.8853900817779268f; // 2*log2(e)

// pack 8 fp32 -> 8 bf16 (RNE) as uint4
static __device__ __forceinline__ uint4 pack8(f32x4 a, f32x4 b) {
    union { uint4 u; __hip_bfloat162 h[4]; } r;
    r.h[0] = __float22bfloat162_rn(make_float2(a.x, a.y));
    r.h[1] = __float22bfloat162_rn(make_float2(a.z, a.w));
    r.h[2] = __float22bfloat162_rn(make_float2(b.x, b.y));
    r.h[3] = __float22bfloat162_rn(make_float2(b.z, b.w));
    return r.u;
}

static __device__ __forceinline__ f32x2 lo2(f32x4 v) { return __builtin_shufflevector(v, v, 0, 1); }
static __device__ __forceinline__ f32x2 hi2(f32x4 v) { return __builtin_shufflevector(v, v, 2, 3); }

// ---------------------------------------------------------------------------
// Kernel 1: bf16 MFMA projection. Retiled 64m x 32n (grid 512 = 2 blocks/CU
// resident) for 2x latency hiding vs the old 1-block/CU 64x64 form.
//   n < 1024:  Ea[m][n] = exp2(C*(acc+b1[n]));  else Eb[m][n-1024] = exp2(C*acc)
// ---------------------------------------------------------------------------
__global__ __launch_bounds__(256, 4) void proj_mfma_kernel(
    const float* __restrict__ lm, const float* __restrict__ W1,
    const float* __restrict__ b1, float* __restrict__ Ea, float* __restrict__ Eb)
{
    __shared__ ushort As[64][136];  // 136 us = 68 dw = 4 mod 32 banks: <=2-way, free
    __shared__ ushort Bs[32][136];

    const int tid  = threadIdx.x;
    const int lane = tid & 63;
    const int w    = tid >> 6;
    const int b    = blockIdx.x;          // 0..511
    const int xcd  = b & 7;
    const int idx  = b >> 3;              // 0..63
    const int nbase = (xcd * 8 + (idx & 7)) * 32;   // 0..2047 (32-wide n-tile)
    const int mbase = (idx >> 3) * 64;              // 0..448
    const int wm   = w * 16;
    const int sel  = nbase >> 10;         // block-uniform: Wa(0)/Wb(1)
    const int nrow = nbase & 1023;

    const int frow = lane & 15;
    const int q8   = (lane >> 4) * 8;

    f32x4 acc[2] = {};

    for (int kb = 0; kb < HH; kb += 128) {
        __syncthreads();
        {   // stage A (64x128 -> 1024 chunks) + B (32x128 -> 512 chunks), 6/thread
            int p = tid;
#pragma unroll
            for (int it = 0; it < 4; ++it, p += 256) {      // A chunks
                const int row = p >> 4, c8 = (p & 15) * 8;
                const float* pa = &lm[(mbase + row) * HH + kb + c8];
                *(uint4*)&As[row][c8] = pack8(*(const f32x4*)pa, *(const f32x4*)(pa + 4));
            }
            int q = tid;
#pragma unroll
            for (int it = 0; it < 2; ++it, q += 256) {      // B chunks
                const int row = q >> 4, c8 = (q & 15) * 8;
                const float* pw = &W1[(nrow + row) * 2048 + sel * 1024 + kb + c8];
                *(uint4*)&Bs[row][c8] = pack8(*(const f32x4*)pw, *(const f32x4*)(pw + 4));
            }
        }
        __syncthreads();

#pragma unroll
        for (int s = 0; s < 4; ++s) {
            const bf16x8 a = *(const bf16x8*)&As[wm + frow][s * 32 + q8];
#pragma unroll
            for (int nf = 0; nf < 2; ++nf) {
                const bf16x8 bb = *(const bf16x8*)&Bs[nf * 16 + frow][s * 32 + q8];
                acc[nf] = __builtin_amdgcn_mfma_f32_16x16x32_bf16(a, bb, acc[nf], 0, 0, 0);
            }
        }
    }

    // D mapping: col=lane&15 (n), row=(lane>>4)*4+reg (m)
    const int col = lane & 15;
    const int rq  = (lane >> 4) * 4;
    const int m0  = mbase + wm + rq;
    const bool isA = sel == 0;            // block-uniform
#pragma unroll
    for (int nf = 0; nf < 2; ++nf) {
        const int nn = (nrow + nf * 16 + col);
        if (isA) {
            const float bb = b1[nn];
#pragma unroll
            for (int r = 0; r < 4; ++r)
                Ea[(m0 + r) * HH + nn] = __builtin_amdgcn_exp2f(C_EXP * (acc[nf][r] + bb));
        } else {
#pragma unroll
            for (int r = 0; r < 4; ++r)
                Eb[(m0 + r) * HH + nn] = __builtin_amdgcn_exp2f(C_EXP * acc[nf][r]);
        }
    }
}

// ---------------------------------------------------------------------------
// Kernel 2: triangular pairwise contraction, 64x64 tile, 4x4 per thread.
// Register-pressure-safe loop order: hoist 8 i-side ds_read_b128 per h4,
// j-side (2 reads) inside the jj loop -> peak live set ~10 float4 + 64 acc
// VGPRs, fits the 168-reg budget of __launch_bounds__(256,3) with no spill.
// All LDS/global accesses via native ext_vector f32x4 so .xy/.zw halves are
// aligned register pairs (v_pk_fma_f32-able). One rcp per pair per 4h.
// ---------------------------------------------------------------------------
__global__ __launch_bounds__(256, 3) void pair_kernel(
    const float* __restrict__ Ea, const float* __restrict__ Eb,
    const float* __restrict__ W2, float* __restrict__ pbuf, int slice)
{
    __shared__ float tl[4][64][32];   // [0]=Ea[j] [1]=Eb[j] [2]=Ea[i] [3]=Eb[i]

    const int tid = threadIdx.x;
    const int tx  = tid & 15;
    const int ty  = tid >> 4;         // 0..15

    int tt = blockIdx.x, bi = 0, rem = TNT;          // triangular decode
    while (tt >= rem) { tt -= rem; --rem; ++bi; }
    const int bj    = bi + tt;
    const int ibase = bi * 64;
    const int jbase = bj * 64;
    const int k0    = blockIdx.y * slice;

    f32x2 acc0[4][4] = {};   // [ii][jj], h-packed partial sums, channel 0
    f32x2 acc1[4][4] = {};   // channel 1
    const f32x2 one2 = {1.f, 1.f};

    for (int kb = 0; kb < slice; kb += 32) {
        if (kb) __syncthreads();
        {   // stage 4 tiles x 64 rows x 32 floats = 2048 float4, 8/thread
            const int c4  = tid & 7;
            const int r0  = tid >> 3;                // 0..31
            const int hof = k0 + kb + c4 * 4;
#pragma unroll
            for (int it = 0; it < 8; ++it) {
                const int tile = it >> 1;            // compile-time per it
                const int row  = (it & 1) * 32 + r0;
                const int base = (tile < 2) ? jbase : ibase;
                const float* src = (tile == 0 || tile == 2) ? Ea : Eb;
                const int c4s = c4 ^ (row & 7);
                *(f32x4*)&tl[tile][row][c4s * 4] =
                    *(const f32x4*)&src[(size_t)(base + row) * HH + hof];
            }
        }
        __syncthreads();

#pragma unroll 1
        for (int h4 = 0; h4 < 8; ++h4) {
            const int sxj = (h4 ^ (tx & 7)) * 4;     // xor-swizzled float4 slot
            const int sxi = (h4 ^ (ty & 7)) * 4;

            // hoisted i-side (broadcast reads), split into pk-ready halves
            f32x2 ailo[4], aihi[4], bilo[4], bihi[4];
#pragma unroll
            for (int ii = 0; ii < 4; ++ii) {
                const f32x4 Ai = *(const f32x4*)&tl[2][ty + 16 * ii][sxi];
                const f32x4 Bi = *(const f32x4*)&tl[3][ty + 16 * ii][sxi];
                ailo[ii] = lo2(Ai); aihi[ii] = hi2(Ai);
                bilo[ii] = lo2(Bi); bihi[ii] = hi2(Bi);
            }
            const f32x4 w0q = *(const f32x4*)&W2[k0 + kb + h4 * 4];      // uniform
            const f32x4 w1q = *(const f32x4*)&W2[HH + k0 + kb + h4 * 4];
            const f32x2 w0lo = lo2(w0q), w0hi = hi2(w0q);
            const f32x2 w1lo = lo2(w1q), w1hi = hi2(w1q);

#pragma unroll
            for (int jj = 0; jj < 4; ++jj) {
                const f32x4 Aj = *(const f32x4*)&tl[0][tx + 16 * jj][sxj];
                const f32x4 Bj = *(const f32x4*)&tl[1][tx + 16 * jj][sxj];
                const f32x2 ajlo = lo2(Aj), ajhi = hi2(Aj);
                const f32x2 bjlo = lo2(Bj), bjhi = hi2(Bj);
#pragma unroll
                for (int ii = 0; ii < 4; ++ii) {
                    // d = 1 + Eb_i*Ea_j ; e = 1 + Ea_i*Eb_j   (h-packed pairs)
                    const f32x2 d01 = __builtin_elementwise_fma(bilo[ii], ajlo, one2);
                    const f32x2 d23 = __builtin_elementwise_fma(bihi[ii], ajhi, one2);
                    const f32x2 e01 = __builtin_elementwise_fma(ailo[ii], bjlo, one2);
                    const f32x2 e23 = __builtin_elementwise_fma(aihi[ii], bjhi, one2);
                    // 1/d + 1/e = (d+e)/(d*e); batch-rcp the 4 products (>=1, no uflow)
                    const f32x2 n01 = d01 + e01, n23 = d23 + e23;
                    const f32x2 m01 = d01 * e01, m23 = d23 * e23;
                    const float p01 = m01.x * m01.y;
                    const float p23 = m23.x * m23.y;
                    const float R   = __builtin_amdgcn_rcpf(p01 * p23);
                    const float r01 = R * p23;       // = 1/p01
                    const float r23 = R * p01;       // = 1/p23
                    const f32x2 u01 = (n01 * __builtin_shufflevector(m01, m01, 1, 0))
                                      * (f32x2){r01, r01};
                    const f32x2 u23 = (n23 * __builtin_shufflevector(m23, m23, 1, 0))
                                      * (f32x2){r23, r23};
                    acc0[ii][jj] = __builtin_elementwise_fma(u01, w0lo, acc0[ii][jj]);
                    acc0[ii][jj] = __builtin_elementwise_fma(u23, w0hi, acc0[ii][jj]);
                    acc1[ii][jj] = __builtin_elementwise_fma(u01, w1lo, acc1[ii][jj]);
                    acc1[ii][jj] = __builtin_elementwise_fma(u23, w1hi, acc1[ii][jj]);
                }
            }
        }
    }

    float* pb = pbuf + ((size_t)blockIdx.y * NTILE + blockIdx.x) * 8192;
#pragma unroll
    for (int ii = 0; ii < 4; ++ii)
#pragma unroll
        for (int jj = 0; jj < 4; ++jj) {
            const int li = ty + 16 * ii, lj = tx + 16 * jj;
            const f32x2 v = { acc0[ii][jj].x + acc0[ii][jj].y,
                              acc1[ii][jj].x + acc1[ii][jj].y };
            *(f32x2*)&pb[(li * 64 + lj) * 2] = v;
        }
}

// ---------------------------------------------------------------------------
// Kernel 3: combine: out = wsum[c]+b2[c] - sum_z pbuf; scatter (i,j),(j,i).
// 1152 blocks over 36 tiles x 64x64x2; 4-way ILP on z.
// ---------------------------------------------------------------------------
__global__ __launch_bounds__(256) void combine_kernel(
    const float* __restrict__ pbuf, const float* __restrict__ W2,
    const float* __restrict__ b2, float* __restrict__ out, int nz)
{
    __shared__ float s_ws[2];

    const int tid = threadIdx.x;
    if (tid < 128) {
        const int c = tid >> 6, l = tid & 63;
        float s = 0.f;
#pragma unroll
        for (int q = 0; q < 4; ++q) {
            const f32x4 v = *(const f32x4*)&W2[c * HH + (l + q * 64) * 4];
            s += v.x + v.y + v.z + v.w;
        }
#pragma unroll
        for (int off = 32; off; off >>= 1) s += __shfl_down(s, off, 64);
        if (l == 0) s_ws[c] = s + b2[c];
    }
    __syncthreads();

    const int idx   = blockIdx.x * 256 + tid;   // 0 .. 36*8192-1
    const int t     = idx >> 13;                // block-uniform (8192/256=32)
    const int local = idx & 8191;
    int tt = t, bi = 0, rem = TNT;
    while (tt >= rem) { tt -= rem; --rem; ++bi; }
    const int bj = bi + tt;

    float s0 = 0.f, s1 = 0.f, s2 = 0.f, s3 = 0.f;
    for (int z = 0; z < nz; z += 4) {   // nz in {8,16,32}
        s0 += pbuf[((size_t)z * NTILE + t) * 8192 + local];
        s1 += pbuf[((size_t)(z + 1) * NTILE + t) * 8192 + local];
        s2 += pbuf[((size_t)(z + 2) * NTILE + t) * 8192 + local];
        s3 += pbuf[((size_t)(z + 3) * NTILE + t) * 8192 + local];
    }
    const float s = (s0 + s1) + (s2 + s3);

    const int li = local >> 7;          // 0..63
    const int lj = (local >> 1) & 63;
    const int c  = local & 1;
    const float v = s_ws[c] - s;

    const int i = bi * 64 + li;
    const int j = bj * 64 + lj;
    out[(i * LL + j) * 2 + c] = v;
    out[(j * LL + i) * 2 + c] = v;   // diagonal tiles: same-value rewrite, benign
}

extern "C" void kernel_launch(void* const* d_in, const int* in_sizes, int n_in,
                              void* d_out, int out_size, void* d_ws, size_t ws_size,
                              hipStream_t stream)
{
    const float* lm = (const float*)d_in[0];
    const float* W1 = (const float*)d_in[1];
    const float* b1 = (const float*)d_in[2];
    const float* W2 = (const float*)d_in[3];
    const float* b2 = (const float*)d_in[4];
    float* out = (float*)d_out;

    char* ws = (char*)d_ws;
    float* Ea   = (float*)ws;                            // 2 MB
    float* Eb   = (float*)(ws + (2u << 20));             // 2 MB
    float* pbuf = (float*)(ws + (4u << 20) + 64);        // nz * 1.18 MB

    const size_t ubase = (4u << 20) + 64;
    const size_t per_z = (size_t)NTILE * 8192 * 4;       // 1.18 MB per z-slice
    int nz = 8;                                          // 288 blocks (safe floor)
    if      (ws_size >= ubase + 32 * per_z) nz = 32;     // 1152 blocks, 4.5/CU
    else if (ws_size >= ubase + 16 * per_z) nz = 16;     // 576 blocks
    const int slice = HH / nz;

    proj_mfma_kernel<<<512, 256, 0, stream>>>(lm, W1, b1, Ea, Eb);
    pair_kernel<<<dim3(NTILE, nz), 256, 0, stream>>>(Ea, Eb, W2, pbuf, slice);
    combine_kernel<<<(NTILE * 8192) / 256, 256, 0, stream>>>(pbuf, W2, b2, out, nz);
}